// Round 4
// baseline (600.641 us; speedup 1.0000x reference)
//
#include <hip/hip_runtime.h>

#define MIN_NORM 1e-15f
#define RCPF(x)  __builtin_amdgcn_rcpf(x)
#define SQRTF(x) __builtin_amdgcn_sqrtf(x)

// butterfly sum within each 16-lane group
__device__ __forceinline__ float rsum16(float v) {
    v += __shfl_xor(v, 1, 64);
    v += __shfl_xor(v, 2, 64);
    v += __shfl_xor(v, 4, 64);
    v += __shfl_xor(v, 8, 64);
    return v;
}

// tanh for x >= 0 via hardware exp
__device__ __forceinline__ float tanh_fast(float x) {
    float ex = __expf(fminf(2.f * x, 30.f));
    return (ex - 1.f) * RCPF(ex + 1.f);
}

// ---------------- CSR build ----------------
__global__ __launch_bounds__(256) void k_count(const int* __restrict__ head,
                                               int* __restrict__ C, int E) {
    int i = blockIdx.x * 256 + (int)threadIdx.x;
    if (i < E) atomicAdd(&C[head[i]], 1);
}

// per-block inclusive scan of C -> T, block totals -> BS
__global__ __launch_bounds__(256) void k_scan1(const int* __restrict__ C,
                                               int* __restrict__ T,
                                               int* __restrict__ BS, int N) {
    __shared__ int lds[256];
    int i = blockIdx.x * 256 + (int)threadIdx.x;
    int v = (i < N) ? C[i] : 0;
    lds[threadIdx.x] = v;
    __syncthreads();
    for (int off = 1; off < 256; off <<= 1) {
        int add = (threadIdx.x >= (unsigned)off) ? lds[threadIdx.x - off] : 0;
        __syncthreads();
        lds[threadIdx.x] += add;
        __syncthreads();
    }
    if (i < N) T[i] = lds[threadIdx.x];
    if (threadIdx.x == 255) BS[blockIdx.x] = lds[255];
}

// single-block exclusive scan of BS (nb <= 1024), in place
__global__ __launch_bounds__(1024) void k_scan2(int* __restrict__ BS, int nb) {
    __shared__ int lds[1024];
    int v = ((int)threadIdx.x < nb) ? BS[threadIdx.x] : 0;
    lds[threadIdx.x] = v;
    __syncthreads();
    for (int off = 1; off < 1024; off <<= 1) {
        int add = (threadIdx.x >= (unsigned)off) ? lds[threadIdx.x - off] : 0;
        __syncthreads();
        lds[threadIdx.x] += add;
        __syncthreads();
    }
    if ((int)threadIdx.x < nb) BS[threadIdx.x] = lds[threadIdx.x] - v;  // exclusive
}

// O[i] = exclusive global offset; P[i] = cursor copy; O[N] = E
__global__ __launch_bounds__(256) void k_scan3(const int* __restrict__ C,
                                               const int* __restrict__ T,
                                               const int* __restrict__ BS,
                                               int* __restrict__ O,
                                               int* __restrict__ P, int N, int E) {
    int i = blockIdx.x * 256 + (int)threadIdx.x;
    if (i < N) {
        int o = T[i] - C[i] + BS[blockIdx.x];
        O[i] = o;
        P[i] = o;
    }
    if (i == 0) O[N] = E;
}

__global__ __launch_bounds__(256) void k_scatter(const int* __restrict__ head,
                                                 const int* __restrict__ tail,
                                                 const int* __restrict__ etype,
                                                 int* __restrict__ P,
                                                 int2* __restrict__ csr, int E) {
    int i = blockIdx.x * 256 + (int)threadIdx.x;
    if (i < E) {
        int pos = atomicAdd(&P[head[i]], 1);
        csr[pos] = make_int2(tail[i], etype[i] - 1);
    }
}

// ------------- fused hop kernel: one wave per head entity -------------
// lane = (s = sub-edge slot 0..3, g = 0..15); lane owns dims {g,g+16,g+32,g+48}
__global__ __launch_bounds__(256) void rgat_hop_kernel(
    const float* __restrict__ e,       // [N,64] current embeddings
    const float* __restrict__ rel,     // [32,64]
    const int2*  __restrict__ csr,     // [(tail, rtype)] in CSR order
    const int*   __restrict__ O,       // [N+1] offsets
    const float* __restrict__ res_in,  // [N,64]
    float*       __restrict__ res_out, // [N,64]
    float*       __restrict__ e_out,   // [N,64] normalized agg (may be null)
    int N)
{
    int wid  = (blockIdx.x * 256 + (int)threadIdx.x) >> 6;
    int lane = (int)threadIdx.x & 63;
    int s    = lane >> 4;
    int g    = lane & 15;
    if (wid >= N) return;

    int beg = O[wid];
    int end = O[wid + 1];

    // head row (shared by all lanes) + p = expmap0(h) scalars, once per head
    const float* hrow = e + (size_t)wid * 64 + g;
    float h[4];
#pragma unroll
    for (int k = 0; k < 4; ++k) h[k] = hrow[k * 16];

    float phh = 0.f;
#pragma unroll
    for (int k = 0; k < 4; ++k) phh += h[k] * h[k];
    float hh = rsum16(phh);

    float nh  = fmaxf(SQRTF(hh), MIN_NORM);
    float th  = tanh_fast(nh);
    float scp = th * RCPF(nh);
    float p2  = th * th;
    float lam_inv = fmaxf(1.f - p2, MIN_NORM);   // = 2/lam = bet = dsf
    float ilam    = RCPF(lam_inv);               // = lam/2
    float bet = 1.f - p2;

    float acc0 = 0.f, acc1 = 0.f, acc2 = 0.f, acc3 = 0.f;

    for (int it = beg; it < end; it += 4) {
        int pos  = it + s;
        bool act = pos < end;
        int pc   = act ? pos : (end - 1);
        int2 tr  = csr[pc];

        const float* trow = e   + (size_t)tr.x * 64 + g;
        const float* rrow = rel + (size_t)tr.y * 64 + g;
        float t[4], r[4], trl[4];
#pragma unroll
        for (int k = 0; k < 4; ++k) { t[k] = trow[k * 16]; r[k] = rrow[k * 16]; }

        float ptt = 0.f, prr = 0.f, pqq = 0.f, pht = 0.f, phr = 0.f;
#pragma unroll
        for (int k = 0; k < 4; ++k) {
            float q = t[k] + r[k];
            trl[k] = q;
            ptt += t[k] * t[k];
            prr += r[k] * r[k];
            pqq += q * q;
            pht += h[k] * t[k];
            phr += h[k] * r[k];
        }
        float tt   = rsum16(ptt);
        float rr   = rsum16(prr);
        float ntr2 = rsum16(pqq);
        float ht   = rsum16(pht);
        float hr   = rsum16(phr);

        // yt = tanh(lam/2*|t|) t/|t|
        float nt  = fmaxf(SQRTF(tt), MIN_NORM);
        float tht = tanh_fast(nt * ilam);
        float sct = tht * RCPF(nt);
        float y2t = tht * tht;
        float xyt = scp * sct * ht;

        float nr   = fmaxf(SQRTF(rr), MIN_NORM);
        float thr_ = tanh_fast(nr * ilam);
        float scr  = thr_ * RCPF(nr);
        float y2r  = thr_ * thr_;
        float xyr  = scp * scr * hr;

        // a = mobius_add(p, yt)
        float alt  = 1.f + 2.f * xyt + y2t;
        float dent = fmaxf(1.f + 2.f * xyt + p2 * y2t, MIN_NORM);
        float idt  = RCPF(dent);
        float a2 = (alt * alt * p2 + 2.f * alt * bet * xyt + bet * bet * y2t) * idt * idt;
        float pa = (alt * p2 + bet * xyt) * idt;

        // b = mobius_add(p, yr)
        float alr  = 1.f + 2.f * xyr + y2r;
        float denr = fmaxf(1.f + 2.f * xyr + p2 * y2r, MIN_NORM);
        float idr  = RCPF(denr);
        float b2 = (alr * alr * p2 + 2.f * alr * bet * xyr + bet * bet * y2r) * idr * idr;
        float pb = (alr * p2 + bet * xyr) * idr;

        // a.b (t.r via parallelogram identity)
        float trd  = 0.5f * (ntr2 - tt - rr);
        float ytyr = sct * scr * trd;
        float ab = (alt * alr * p2 + alt * bet * xyr + bet * alr * xyt + bet * bet * ytyr) * idt * idr;

        // m = mobius_add(a, b)
        float am   = 1.f + 2.f * ab + b2;
        float bm   = 1.f - a2;
        float denm = fmaxf(1.f + 2.f * ab + a2 * b2, MIN_NORM);
        float idm  = RCPF(denm);
        float m2  = (am * am * a2 + 2.f * am * bm * ab + bm * bm * b2) * idm * idm;
        float pmv = (am * pa + bm * pb) * idm;

        // project(m) — branchless
        float nm = fmaxf(SQRTF(m2), MIN_NORM);
        const float maxn = 1.f - 4e-3f;
        float sc = (nm > maxn) ? (maxn * RCPF(nm)) : 1.f;
        m2  *= sc * sc;
        pmv *= sc;

        // logmap scalars
        float cs   = 1.f - 2.f * pmv + m2;
        float dens = fmaxf(1.f - 2.f * pmv + p2 * m2, MIN_NORM);
        float ids  = RCPF(dens);
        float s2 = (cs * cs * p2 - 2.f * cs * bet * pmv + bet * bet * m2) * ids * ids;
        float ns  = fmaxf(SQRTF(s2), MIN_NORM);
        float xa  = fminf(ns, 1.f - 1e-7f);
        float ath = 0.5f * __logf((1.f + xa) * RCPF(1.f - xa));
        float lgs = lam_inv * ath * RCPF(ns);

        float iric = RCPF(fmaxf(SQRTF(ntr2), 1e-12f));

        float amask = act ? 1.f : 0.f;
#pragma unroll
        for (int k = 0; k < 4; ++k) {
            float p_l = scp * h[k];
            float a_l = (alt * p_l + bet * (sct * t[k])) * idt;
            float b_l = (alr * p_l + bet * (scr * r[k])) * idr;
            float m_l = (am * a_l + bm * b_l) * idm * sc;
            float s_l = (cs * (-p_l) + bet * m_l) * ids;
            float res = fmaxf(lgs * s_l + 1e-7f * (trl[k] * iric), 0.f) * amask;
            if (k == 0) acc0 += res;
            else if (k == 1) acc1 += res;
            else if (k == 2) acc2 += res;
            else acc3 += res;
        }
    }

    // sum the 4 sub-edge accumulators across sub groups (xor 16, 32)
    acc0 += __shfl_xor(acc0, 16, 64); acc0 += __shfl_xor(acc0, 32, 64);
    acc1 += __shfl_xor(acc1, 16, 64); acc1 += __shfl_xor(acc1, 32, 64);
    acc2 += __shfl_xor(acc2, 16, 64); acc2 += __shfl_xor(acc2, 32, 64);
    acc3 += __shfl_xor(acc3, 16, 64); acc3 += __shfl_xor(acc3, 32, 64);

    // l2 normalize (scatter-mean count cancels under normalize)
    float pn = acc0 * acc0 + acc1 * acc1 + acc2 * acc2 + acc3 * acc3;
    float n2 = rsum16(pn);
    float inv = RCPF(fmaxf(SQRTF(n2), 1e-12f));

    // lane (s,g) writes dim s*16+g == lane; value = acc_s * inv (static select)
    float vsel = (s == 0) ? acc0 : ((s == 1) ? acc1 : ((s == 2) ? acc2 : acc3));
    float vdim = vsel * inv;

    size_t idx = (size_t)wid * 64 + lane;
    if (e_out) e_out[idx] = vdim;
    res_out[idx] = 0.5f * res_in[idx] + vdim;
}

extern "C" void kernel_launch(void* const* d_in, const int* in_sizes, int n_in,
                              void* d_out, int out_size, void* d_ws, size_t ws_size,
                              hipStream_t stream)
{
    const float* ent   = (const float*)d_in[0];   // [N,64]
    const float* rel   = (const float*)d_in[1];   // [32,64]
    const int*   eidx  = (const int*)d_in[2];     // [2,E]
    const int*   etype = (const int*)d_in[3];     // [E]

    int E = in_sizes[3];
    int N = in_sizes[0] / 64;
    const int* head = eidx;
    const int* tail = eidx + E;

    // workspace layout (8B alignment maintained)
    float* A   = (float*)d_ws;                    // [N*64] hop-1 normalized e
    int2*  csr = (int2*)(A + (size_t)N * 64);     // [E]
    int*   O   = (int*)(csr + E);                 // [N+1]
    int*   P   = O + (N + 1);                     // [N]
    int*   C   = P + N;                           // [N]
    int*   T   = C + N;                           // [N]
    int*   BS  = T + N;                           // [<=1024]

    int NB = (N + 255) / 256;   // 782 for N=200000 (must be <= 1024)
    int EB = (E + 255) / 256;

    hipMemsetAsync(C, 0, (size_t)N * sizeof(int), stream);

    // CSR build (reused by both hops)
    k_count  <<<EB, 256, 0, stream>>>(head, C, E);
    k_scan1  <<<NB, 256, 0, stream>>>(C, T, BS, N);
    k_scan2  <<<1, 1024, 0, stream>>>(BS, NB);
    k_scan3  <<<NB, 256, 0, stream>>>(C, T, BS, O, P, N, E);
    k_scatter<<<EB, 256, 0, stream>>>(head, tail, etype, P, csr, E);

    float* out = (float*)d_out;
    int hopGrid = (N + 3) / 4;   // 4 waves/block, 1 wave per head

    // hop 1: e = ent, out = 0.5*ent + e1norm, A = e1norm
    rgat_hop_kernel<<<hopGrid, 256, 0, stream>>>(ent, rel, csr, O, ent, out, A, N);
    // hop 2: e = A, out = 0.5*out + e2norm
    rgat_hop_kernel<<<hopGrid, 256, 0, stream>>>(A, rel, csr, O, out, out, nullptr, N);
}

// Round 5
// 494.268 us; speedup vs baseline: 1.2152x; 1.2152x over previous
//
#include <hip/hip_runtime.h>

#define MIN_NORM 1e-15f
#define RCPF(x)  __builtin_amdgcn_rcpf(x)
#define SQRTF(x) __builtin_amdgcn_sqrtf(x)
#define RSQF(x)  __builtin_amdgcn_rsqf(x)

// butterfly sum within each 16-lane group via DPP row_ror (pure VALU, no LDS pipe)
__device__ __forceinline__ float rsum16(float v) {
    v += __int_as_float(__builtin_amdgcn_update_dpp(0, __float_as_int(v), 0x121, 0xF, 0xF, false)); // ror:1
    v += __int_as_float(__builtin_amdgcn_update_dpp(0, __float_as_int(v), 0x122, 0xF, 0xF, false)); // ror:2
    v += __int_as_float(__builtin_amdgcn_update_dpp(0, __float_as_int(v), 0x124, 0xF, 0xF, false)); // ror:4
    v += __int_as_float(__builtin_amdgcn_update_dpp(0, __float_as_int(v), 0x128, 0xF, 0xF, false)); // ror:8
    return v;
}

// tanh for x >= 0 via hardware exp
__device__ __forceinline__ float tanh_fast(float x) {
    float ex = __expf(fminf(2.f * x, 30.f));
    return (ex - 1.f) * RCPF(ex + 1.f);
}

// per-entity head/tail scalars: {scp, p2, nt, inv_nt}
__device__ __forceinline__ float4 prep_scalars(float n2) {
    float nh     = fmaxf(SQRTF(fmaxf(n2, 0.f)), MIN_NORM);
    float inv_nh = RCPF(nh);
    float th     = tanh_fast(nh);
    return make_float4(th * inv_nh, th * th, nh, inv_nh);
}

// build entity table from raw embeddings (hop 1)
__global__ __launch_bounds__(256) void k_prep(const float4* __restrict__ src,
                                              float4* __restrict__ T, int N) {
    int gid = (blockIdx.x * 256 + (int)threadIdx.x) >> 4;
    int g   = (int)threadIdx.x & 15;
    if (gid >= N) return;
    float4 v = src[(size_t)gid * 16 + g];
    float n2 = rsum16(v.x * v.x + v.y * v.y + v.z * v.z + v.w * v.w);
    if (g == 0) T[gid] = prep_scalars(n2);
}

// relation table: {nr, inv_nr, rr, 0}
__global__ __launch_bounds__(256) void k_prep_rel(const float4* __restrict__ rel,
                                                  float4* __restrict__ RelC, int NR) {
    int gid = (blockIdx.x * 256 + (int)threadIdx.x) >> 4;
    int g   = (int)threadIdx.x & 15;
    if (gid >= NR) return;
    float4 v = rel[(size_t)gid * 16 + g];
    float n2 = rsum16(v.x * v.x + v.y * v.y + v.z * v.z + v.w * v.w);
    if (g == 0) {
        float nr = fmaxf(SQRTF(n2), MIN_NORM);
        RelC[gid] = make_float4(nr, RCPF(nr), n2, 0.f);
    }
}

// one 16-lane group per edge; lane g owns dims {g, g+16, g+32, g+48}
__global__ __launch_bounds__(256) void rgat_edge_kernel(
    const float*  __restrict__ e,      // [N,64] current embeddings
    const float*  __restrict__ rel,    // [32,64]
    const float4* __restrict__ T,      // [N] {scp,p2,nt,inv_nt}
    const float4* __restrict__ RelC,   // [32] {nr,inv_nr,rr,0}
    const int*    __restrict__ head,
    const int*    __restrict__ tail,
    const int*    __restrict__ etype,  // 1-based
    float*        __restrict__ sums,   // [N,64] pre-zeroed (= d_out)
    int E)
{
    int tid = blockIdx.x * 256 + (int)threadIdx.x;
    int eid = tid >> 4;
    int g   = (int)threadIdx.x & 15;
    if (eid >= E) return;

    int hi = head[eid];
    int ti = tail[eid];
    int ri = etype[eid] - 1;

    float4 Th = T[hi];      // .x=scp .y=p2
    float4 Tt = T[ti];      // .z=nt  .w=inv_nt
    float4 Rc = RelC[ri];   // .x=nr  .y=inv_nr .z=rr
    float scp = Th.x, p2 = Th.y;
    float nt = Tt.z, inv_nt = Tt.w;
    float nr = Rc.x, inv_nr = Rc.y, rr = Rc.z;

    const float* hrow = e   + (size_t)hi * 64 + g;
    const float* trow = e   + (size_t)ti * 64 + g;
    const float* rrow = rel + (size_t)ri * 64 + g;

    float h[4], t[4], r[4], trl[4];
#pragma unroll
    for (int k = 0; k < 4; ++k) {
        h[k] = hrow[k * 16];
        t[k] = trow[k * 16];
        r[k] = rrow[k * 16];
    }

    float pht = 0.f, phr = 0.f, ptr_ = 0.f;
#pragma unroll
    for (int k = 0; k < 4; ++k) {
        trl[k] = t[k] + r[k];
        pht += h[k] * t[k];
        phr += h[k] * r[k];
        ptr_ += t[k] * r[k];
    }
    float ht  = rsum16(pht);
    float hr  = rsum16(phr);
    float ttr = rsum16(ptr_);

    float tt   = nt * nt;
    float ntr2 = fmaf(2.f, ttr, tt + rr);        // |t+r|^2
    float bet  = fmaxf(1.f - p2, MIN_NORM);      // = lam_inv
    float ilam = RCPF(bet);                      // = lam/2

    float tht = tanh_fast(ilam * nt);
    float sct = tht * inv_nt;
    float y2t = tht * tht;
    float xyt = scp * sct * ht;

    float thr_ = tanh_fast(ilam * nr);
    float scr  = thr_ * inv_nr;
    float y2r  = thr_ * thr_;
    float xyr  = scp * scr * hr;

    // a = mobius_add(p, yt), b = mobius_add(p, yr)
    float alt  = fmaf(2.f, xyt, 1.f + y2t);
    float dent = fmaxf(fmaf(p2, y2t, fmaf(2.f, xyt, 1.f)), MIN_NORM);
    float alr  = fmaf(2.f, xyr, 1.f + y2r);
    float denr = fmaxf(fmaf(p2, y2r, fmaf(2.f, xyr, 1.f)), MIN_NORM);
    float iS   = RCPF(dent * denr);
    float idt  = iS * denr;
    float idr  = iS * dent;

    float a2 = (alt * alt * p2 + 2.f * alt * bet * xyt + bet * bet * y2t) * idt * idt;
    float pa = fmaf(bet, xyt, alt * p2) * idt;
    float b2 = (alr * alr * p2 + 2.f * alr * bet * xyr + bet * bet * y2r) * idr * idr;
    float pb = fmaf(bet, xyr, alr * p2) * idr;

    float ytyr = sct * scr * ttr;
    float ab = (alt * alr * p2 + alt * bet * xyr + bet * alr * xyt + bet * bet * ytyr) * idt * idr;

    // m = mobius_add(a, b)
    float am   = fmaf(2.f, ab, 1.f + b2);
    float bm   = 1.f - a2;
    float denm = fmaxf(fmaf(a2, b2, fmaf(2.f, ab, 1.f)), MIN_NORM);
    float idm  = RCPF(denm);
    float m2  = (am * am * a2 + 2.f * am * bm * ab + bm * bm * b2) * idm * idm;
    float pmv = fmaf(am, pa, bm * pb) * idm;

    // project via m2 compare (no sqrt)
    const float maxn  = 1.f - 4e-3f;
    const float maxn2 = maxn * maxn;
    float irm = RSQF(fmaxf(m2, 1e-30f));
    float sc  = (m2 > maxn2) ? (maxn * irm) : 1.f;
    m2  *= sc * sc;
    pmv *= sc;

    // logmap scalars
    float cs   = fmaf(-2.f, pmv, 1.f + m2);
    float dens = fmaxf(fmaf(p2, m2, fmaf(-2.f, pmv, 1.f)), MIN_NORM);
    float ids  = RCPF(dens);
    float s2  = fmaxf((cs * cs * p2 - 2.f * cs * bet * pmv + bet * bet * m2) * ids * ids, 1e-30f);
    float irs = RSQF(s2);
    float ns  = s2 * irs;                         // sqrt(s2)
    float xa  = fminf(ns, 1.f - 1e-7f);
    float ath = 0.5f * __logf((1.f + xa) * RCPF(1.f - xa));
    float lgs = bet * ath * irs;                  // lam_inv * artanh(ns)/ns

    float iric = RSQF(fmaxf(ntr2, 1e-24f));

    float bst = bet * sct, bsr = bet * scr, idms = idm * sc;
    float* dst = &sums[(size_t)hi * 64 + g];
#pragma unroll
    for (int k = 0; k < 4; ++k) {
        float p_l = scp * h[k];
        float a_l = fmaf(alt, p_l, bst * t[k]) * idt;
        float b_l = fmaf(alr, p_l, bsr * r[k]) * idr;
        float m_l = fmaf(am, a_l, bm * b_l) * idms;
        float s_l = (bet * m_l - cs * p_l) * ids;
        float res = fmaxf(fmaf(lgs, s_l, 1e-7f * (trl[k] * iric)), 0.f);
        atomicAdd(dst + k * 16, res);
    }
}

// hop-1 epilogue: e1n = normalize(sums); write A and refresh table T for hop 2
__global__ __launch_bounds__(256) void k_entity1(const float4* __restrict__ sums,
                                                 float4* __restrict__ A,
                                                 float4* __restrict__ T, int N) {
    int gid = (blockIdx.x * 256 + (int)threadIdx.x) >> 4;
    int g   = (int)threadIdx.x & 15;
    if (gid >= N) return;
    size_t idx = (size_t)gid * 16 + g;
    float4 s = sums[idx];
    float n2 = rsum16(s.x * s.x + s.y * s.y + s.z * s.z + s.w * s.w);
    float inv = RCPF(fmaxf(SQRTF(n2), 1e-12f));
    float4 v = make_float4(s.x * inv, s.y * inv, s.z * inv, s.w * inv);
    A[idx] = v;
    float n2v = rsum16(v.x * v.x + v.y * v.y + v.z * v.z + v.w * v.w);
    if (g == 0) T[gid] = prep_scalars(n2v);
}

// hop-2 epilogue (in place on d_out): out = 0.25*ent + 0.5*e1n + normalize(sums2)
__global__ __launch_bounds__(256) void k_entity2(float4* __restrict__ out,
                                                 const float4* __restrict__ ent,
                                                 const float4* __restrict__ A, int N) {
    int gid = (blockIdx.x * 256 + (int)threadIdx.x) >> 4;
    int g   = (int)threadIdx.x & 15;
    if (gid >= N) return;
    size_t idx = (size_t)gid * 16 + g;
    float4 s = out[idx];
    float n2 = rsum16(s.x * s.x + s.y * s.y + s.z * s.z + s.w * s.w);
    float inv = RCPF(fmaxf(SQRTF(n2), 1e-12f));
    float4 en = ent[idx];
    float4 a  = A[idx];
    float4 o;
    o.x = fmaf(0.25f, en.x, fmaf(0.5f, a.x, s.x * inv));
    o.y = fmaf(0.25f, en.y, fmaf(0.5f, a.y, s.y * inv));
    o.z = fmaf(0.25f, en.z, fmaf(0.5f, a.z, s.z * inv));
    o.w = fmaf(0.25f, en.w, fmaf(0.5f, a.w, s.w * inv));
    out[idx] = o;
}

extern "C" void kernel_launch(void* const* d_in, const int* in_sizes, int n_in,
                              void* d_out, int out_size, void* d_ws, size_t ws_size,
                              hipStream_t stream)
{
    const float* ent   = (const float*)d_in[0];   // [N,64]
    const float* rel   = (const float*)d_in[1];   // [32,64]
    const int*   eidx  = (const int*)d_in[2];     // [2,E]
    const int*   etype = (const int*)d_in[3];     // [E]

    int E = in_sizes[3];
    int N = in_sizes[0] / 64;
    int NR = in_sizes[1] / 64;
    const int* head = eidx;
    const int* tail = eidx + E;

    // ws: A [N*64 f32] | T [N float4] | RelC [NR float4]   (~54.5 MB)
    float*  A    = (float*)d_ws;
    float4* T    = (float4*)(A + (size_t)N * 64);
    float4* RelC = T + N;

    float* out = (float*)d_out;
    size_t embBytes = (size_t)N * 64 * sizeof(float);

    dim3 blk(256);
    int prepGrid = (N * 16 + 255) / 256;    // 16 lanes per entity
    int relGrid  = (NR * 16 + 255) / 256;
    int edgeGrid = (E * 16 + 255) / 256;    // 16 lanes per edge

    // tables for hop 1
    k_prep    <<<prepGrid, blk, 0, stream>>>((const float4*)ent, T, N);
    k_prep_rel<<<relGrid,  blk, 0, stream>>>((const float4*)rel, RelC, NR);

    // hop 1: scatter into d_out, then normalize -> A, refresh T
    hipMemsetAsync(out, 0, embBytes, stream);
    rgat_edge_kernel<<<edgeGrid, blk, 0, stream>>>(ent, rel, T, RelC, head, tail, etype, out, E);
    k_entity1<<<prepGrid, blk, 0, stream>>>((const float4*)out, (float4*)A, T, N);

    // hop 2: scatter into d_out, then fuse residual in place
    hipMemsetAsync(out, 0, embBytes, stream);
    rgat_edge_kernel<<<edgeGrid, blk, 0, stream>>>(A, rel, T, RelC, head, tail, etype, out, E);
    k_entity2<<<prepGrid, blk, 0, stream>>>((float4*)out, (const float4*)ent, (const float4*)A, N);
}